// Round 7
// baseline (215.201 us; speedup 1.0000x reference)
//
#include <hip/hip_runtime.h>

// TV-L1 optical flow, B=4, 512x512, 20 iters.
// R7: register-resident state + LDS boundary publications, 2 launches x 10
// fused iterations. 768 threads = 24x32 thread grid; each thread owns a
// 4-row x 3-col pixel block of a 96x96 region (tile 64 + halo L=11/R=21).
// All u/p state in VGPRs; cross-thread neighbor access via small LDS "pub"
// arrays (own boundary rows/cols), one barrier per phase. Guard-free cone
// (validated R6): garbage outside the halo never reaches the interior.
// Kernel A (mode 0): init from x, 10 iters, write state. Kernel B (mode 1):
// load state, 10 u- + 9 p-phases (20th p dead), fused 3x3 avgpool -> out.

typedef float v2f __attribute__((ext_vector_type(2)));

#define HH 512
#define WW 512
#define BB 4
constexpr int HW = HH * WW;
constexpr float EPS = 1e-8f;

#define RG 96         // region edge = 64 + 11 + 21
#define LH 11         // left/top halo
#define TPB 768       // 24x32 thread grid, 12 waves
#define TC 32         // thread cols
#define TR 24         // thread rows
#define PR 4          // px rows per thread
#define PC 3          // px cols per thread
#define NBLK 256      // 4 images x 8x8 tiles of 64
#define XS 98         // x1 staging edge (region + 1-ring)
#define XN (XS * XS)  // 9604

// LDS pub layout (v2f units):
//   paL [96][32] @ 0      paR [96][32] @ 3072   uLp [96][32] @ 6144
//   pbT [24][96] @ 9216   pbB [24][96] @ 11520  uTp [24][96] @ 13824
// total 16128 v2f = 129024 B. Aliases (barrier-ordered lifetimes):
//   x-staging float[9604] @ 0 (38.4 KB), final su v2f[96*96] @ 0 (73.7 KB).

__global__ __launch_bounds__(TPB, 1) void k_big(
    const float* __restrict__ x,
    v2f* __restrict__ ug, float4* __restrict__ pg,
    const float* __restrict__ lam_p, const float* __restrict__ tau_p,
    const float* __restrict__ theta_p,
    const float* __restrict__ wxp, const float* __restrict__ wyp,
    float* __restrict__ out, int mode)
{
    __shared__ __align__(16) char smem[129024];
    v2f* paL = (v2f*)(smem);
    v2f* paR = (v2f*)(smem) + 3072;
    v2f* uLp = (v2f*)(smem) + 6144;
    v2f* pbT = (v2f*)(smem) + 9216;
    v2f* pbB = (v2f*)(smem) + 11520;
    v2f* uTp = (v2f*)(smem) + 13824;
    float* stg = (float*)smem;
    v2f*   su  = (v2f*)smem;

    const int tid = threadIdx.x;
    const int c   = tid & 31;         // thread col
    const int r   = tid >> 5;         // thread row
    const int blk = blockIdx.x;
    const int bimg = blk >> 6;
    const int t    = blk & 63;
    const int gi0  = (t >> 3) * 64;
    const int gj0  = (t & 7) * 64;

    const float lam = lam_p[0], theta = theta_p[0];
    const float rr  = tau_p[0] / theta;
    const float tl  = theta * lam;
    const float wx0 = wxp[0], wx1 = wxp[1], wx2 = wxp[2];
    const float wy0 = wyp[0], wy1 = wyp[1], wy2 = wyp[2];

    const float* x0p = x + (size_t)bimg * 2 * HW;
    const float* x1p = x0p + HW;
    const int gbase = bimg * HW;

    // own region px: rows ri0..ri0+3, cols cj0..cj0+2
    const int ri0 = r * PR, cj0 = c * PC;
    int  giA[PR], gjA[PC];
    bool rIn[PR], cIn[PC];
    #pragma unroll
    for (int i = 0; i < PR; ++i) { giA[i] = gi0 + ri0 + i - LH; rIn[i] = (unsigned)giA[i] < HH; }
    #pragma unroll
    for (int j = 0; j < PC; ++j) { gjA[j] = gj0 + cj0 + j - LH; cIn[j] = (unsigned)gjA[j] < WW; }

    // clamped neighbor-thread indices (edge garbage stays outside the cone)
    const int cL = (c > 0)  ? c - 1 : 0;
    const int cR = (c < TC - 1) ? c + 1 : TC - 1;
    const int rU = (r > 0)  ? r - 1 : 0;
    const int rD = (r < TR - 1) ? r + 1 : TR - 1;

    // ---- pass 1: stage x1 (98x98, zero-padded) into LDS ------------------
    #pragma unroll
    for (int s = 0; s < 13; ++s) {
        int idx = tid + s * TPB;
        if (idx < XN) {
            int li = idx / XS, lj = idx - li * XS;
            int gi = gi0 + li - (LH + 1), gj = gj0 + lj - (LH + 1);
            bool in = ((unsigned)gi < HH) & ((unsigned)gj < WW);
            stg[idx] = in ? x1p[gi * WW + gj] : 0.f;
        }
    }
    __syncthreads();

    // ---- pass 2: statics per own px (from staged x1 + global x0) ---------
    v2f  g[PR][PC];
    float rc[PR][PC], nmv[PR][PC];
    #pragma unroll
    for (int i = 0; i < PR; ++i) {
        #pragma unroll
        for (int j = 0; j < PC; ++j) {
            int sc = (ri0 + i + 1) * XS + (cj0 + j + 1);
            float a00 = stg[sc - XS - 1], a01 = stg[sc - XS], a02 = stg[sc - XS + 1];
            float a10 = stg[sc - 1],      a11 = stg[sc],      a12 = stg[sc + 1];
            float a20 = stg[sc + XS - 1], a21 = stg[sc + XS], a22 = stg[sc + XS + 1];
            const float c6 = 1.f / 6.f;
            float gx = c6 * (-a00 + a02 - 2.f * a10 + 2.f * a12 - a20 + a22);
            float gy = c6 * (-a00 - 2.f * a01 - a02 + a20 + 2.f * a21 + a22);
            g[i][j].x = gx; g[i][j].y = gy;
            nmv[i][j] = gx * gx + gy * gy + EPS;
            bool in = rIn[i] && cIn[j];
            float x0v = in ? x0p[giA[i] * WW + gjA[j]] : 0.f;
            rc[i][j] = a11 - x0v;
        }
    }
    __syncthreads();

    // ---- pass 3: state init (mode 0: zeros+zero pubs; mode 1: load) ------
    v2f u[PR][PC], pa[PR][PC], pb[PR][PC];
    if (mode == 0) {
        #pragma unroll
        for (int i = 0; i < PR; ++i)
            #pragma unroll
            for (int j = 0; j < PC; ++j) {
                u[i][j] = (v2f)(0.f); pa[i][j] = (v2f)(0.f); pb[i][j] = (v2f)(0.f);
            }
        v2f* sm = (v2f*)smem;
        #pragma unroll
        for (int s = 0; s < 21; ++s) {
            int idx = tid + s * TPB;
            if (idx < 16128) sm[idx] = (v2f)(0.f);
        }
    } else {
        #pragma unroll
        for (int i = 0; i < PR; ++i) {
            #pragma unroll
            for (int j = 0; j < PC; ++j) {
                v2f uv = (v2f)(0.f);
                float4 p4 = make_float4(0.f, 0.f, 0.f, 0.f);
                if (rIn[i] && cIn[j]) {
                    int gl = gbase + giA[i] * WW + gjA[j];
                    uv = ug[gl]; p4 = pg[gl];
                }
                u[i][j] = uv;
                pa[i][j].x = p4.x; pa[i][j].y = p4.y;
                pb[i][j].x = p4.z; pb[i][j].y = p4.w;
            }
        }
        // publish p boundaries for the first u-phase
        #pragma unroll
        for (int i = 0; i < PR; ++i) {
            paL[(ri0 + i) * TC + c] = pa[i][0];
            paR[(ri0 + i) * TC + c] = pa[i][PC - 1];
        }
        #pragma unroll
        for (int j = 0; j < PC; ++j) {
            pbT[r * RG + cj0 + j] = pb[0][j];
            pbB[r * RG + cj0 + j] = pb[PR - 1][j];
        }
    }
    __syncthreads();

    // ---- 10 fused iterations --------------------------------------------
    for (int it = 0; it < 10; ++it) {
        // ---- u-phase: reads p pubs, writes u pubs ----
        v2f paln[PR], parn[PR], pbun[PC], pbdn[PC];
        #pragma unroll
        for (int i = 0; i < PR; ++i) {
            paln[i] = paR[(ri0 + i) * TC + cL];   // p col cj0-1
            parn[i] = paL[(ri0 + i) * TC + cR];   // p col cj0+3
        }
        #pragma unroll
        for (int j = 0; j < PC; ++j) {
            pbun[j] = pbB[rU * RG + cj0 + j];     // p row ri0-1
            pbdn[j] = pbT[rD * RG + cj0 + j];     // p row ri0+4
        }
        #pragma unroll
        for (int i = 0; i < PR; ++i) {
            #pragma unroll
            for (int j = 0; j < PC; ++j) {
                v2f uv = u[i][j];
                float rho = rc[i][j] + g[i][j].x * uv.x + g[i][j].y * uv.y;
                float th  = tl * nmv[i][j];
                float d = (fabsf(rho) < th) ? rho * __builtin_amdgcn_rcpf(nmv[i][j])
                                            : copysignf(tl, rho);
                v2f paW = (j == 0)      ? paln[i] : pa[i][j - 1];
                v2f paE = (j == PC - 1) ? parn[i] : pa[i][j + 1];
                v2f pbN = (i == 0)      ? pbun[j] : pb[i - 1][j];
                v2f pbS = (i == PR - 1) ? pbdn[j] : pb[i + 1][j];
                v2f div = wx0 * paW + wx1 * pa[i][j] + wx2 * paE
                        + wy0 * pbN + wy1 * pb[i][j] + wy2 * pbS;
                v2f nu = uv - d * g[i][j] + theta * div;
                if (!(rIn[i] && cIn[j])) nu = (v2f)(0.f);   // zero-pad semantics
                u[i][j] = nu;
            }
        }
        // publish u left col + top row (consumed by left/upper threads)
        #pragma unroll
        for (int i = 0; i < PR; ++i) uLp[(ri0 + i) * TC + c] = u[i][0];
        #pragma unroll
        for (int j = 0; j < PC; ++j) uTp[r * RG + cj0 + j] = u[0][j];
        __syncthreads();

        if (mode == 1 && it == 9) break;   // 20th p-update is dead code

        // ---- p-phase: reads u pubs, writes p pubs ----
        v2f urn[PR], udn[PC];
        #pragma unroll
        for (int i = 0; i < PR; ++i) urn[i] = uLp[(ri0 + i) * TC + cR];  // u col cj0+3
        #pragma unroll
        for (int j = 0; j < PC; ++j) udn[j] = uTp[rD * RG + cj0 + j];    // u row ri0+4
        #pragma unroll
        for (int i = 0; i < PR; ++i) {
            #pragma unroll
            for (int j = 0; j < PC; ++j) {
                v2f uc = u[i][j];
                v2f uE = (j == PC - 1) ? urn[i] : u[i][j + 1];
                v2f uS = (i == PR - 1) ? udn[j] : u[i + 1][j];
                v2f gx_ = uE - uc;
                v2f gy_ = uS - uc;
                float d1 = 1.f + rr * (fabsf(gx_.x) + fabsf(gy_.x));
                float d2 = 1.f + rr * (fabsf(gx_.y) + fabsf(gy_.y));
                v2f iden;
                iden.x = __builtin_amdgcn_rcpf(d1);
                iden.y = __builtin_amdgcn_rcpf(d2);
                v2f npa = (pa[i][j] + rr * gx_) * iden;
                v2f npb = (pb[i][j] + rr * gy_) * iden;
                if (!(rIn[i] && cIn[j])) { npa = (v2f)(0.f); npb = (v2f)(0.f); }
                pa[i][j] = npa; pb[i][j] = npb;
            }
        }
        #pragma unroll
        for (int i = 0; i < PR; ++i) {
            paL[(ri0 + i) * TC + c] = pa[i][0];
            paR[(ri0 + i) * TC + c] = pa[i][PC - 1];
        }
        #pragma unroll
        for (int j = 0; j < PC; ++j) {
            pbT[r * RG + cj0 + j] = pb[0][j];
            pbB[r * RG + cj0 + j] = pb[PR - 1][j];
        }
        __syncthreads();
    }

    // ---- epilogue --------------------------------------------------------
    if (mode == 0) {
        // write interior state [11,74]^2 (always in-image)
        #pragma unroll
        for (int i = 0; i < PR; ++i) {
            #pragma unroll
            for (int j = 0; j < PC; ++j) {
                int ri = ri0 + i, cj = cj0 + j;
                if ((unsigned)(ri - LH) < 64 && (unsigned)(cj - LH) < 64) {
                    int gl = gbase + giA[i] * WW + gjA[j];
                    ug[gl] = u[i][j];
                    pg[gl] = make_float4(pa[i][j].x, pa[i][j].y, pb[i][j].x, pb[i][j].y);
                }
            }
        }
    } else {
        // dump u^20 to LDS (aliases dead pubs), then 3x3 avgpool (/9 always)
        #pragma unroll
        for (int i = 0; i < PR; ++i)
            #pragma unroll
            for (int j = 0; j < PC; ++j)
                su[(ri0 + i) * RG + cj0 + j] = u[i][j];
        __syncthreads();
        const float inv9 = 1.f / 9.f;
        #pragma unroll
        for (int i = 0; i < PR; ++i) {
            #pragma unroll
            for (int j = 0; j < PC; ++j) {
                int ri = ri0 + i, cj = cj0 + j;
                if ((unsigned)(ri - LH) < 64 && (unsigned)(cj - LH) < 64) {
                    int sc = ri * RG + cj;
                    v2f acc = su[sc - RG - 1] + su[sc - RG] + su[sc - RG + 1]
                            + su[sc - 1]      + su[sc]      + su[sc + 1]
                            + su[sc + RG - 1] + su[sc + RG] + su[sc + RG + 1];
                    int gl = giA[i] * WW + gjA[j];
                    out[(size_t)bimg * 2 * HW + gl]      = acc.x * inv9;
                    out[(size_t)bimg * 2 * HW + HW + gl] = acc.y * inv9;
                }
            }
        }
    }
}

// --------------------------------------------------------------- launch ---
extern "C" void kernel_launch(void* const* d_in, const int* in_sizes, int n_in,
                              void* d_out, int out_size, void* d_ws, size_t ws_size,
                              hipStream_t stream) {
    const float* x     = (const float*)d_in[0];
    const float* lam   = (const float*)d_in[1];
    const float* tau   = (const float*)d_in[2];
    const float* theta = (const float*)d_in[3];
    const float* wx    = (const float*)d_in[4];
    const float* wy    = (const float*)d_in[5];
    float* out = (float*)d_out;

    float*  ws = (float*)d_ws;
    v2f*    ug = (v2f*)ws;                                    // 8 MB
    float4* pg = (float4*)(ws + (size_t)2 * BB * HW);         // 16 MB

    k_big<<<dim3(NBLK), dim3(TPB), 0, stream>>>(
        x, ug, pg, lam, tau, theta, wx, wy, out, 0);
    k_big<<<dim3(NBLK), dim3(TPB), 0, stream>>>(
        x, ug, pg, lam, tau, theta, wx, wy, out, 1);
}